// Round 2
// 947.859 us; speedup vs baseline: 1.0401x; 1.0401x over previous
//
#include <hip/hip_runtime.h>

// P=4096, LMAX=64, D=512, H=512
typedef __attribute__((ext_vector_type(8))) short bf16x8;
typedef __attribute__((ext_vector_type(8))) unsigned short u16x8;
typedef __attribute__((ext_vector_type(4))) float f32x4;

__device__ __forceinline__ ushort f2bf(float x) {
  unsigned u = __float_as_uint(x);
  unsigned r = (u + 0x7fffu + ((u >> 16) & 1u)) >> 16;
  return (ushort)r;
}

// async global->LDS, 16B per lane. LDS base must be wave-uniform (lane0 slot):
// HW writes lane l at base + l*16. We only ever issue this with a FULL exec
// mask (all skip decisions are wave-uniform) — partial-exec DMA placement is
// unverified on gfx950, so we avoid it entirely.
typedef const __attribute__((address_space(1))) unsigned int ga_uint;
typedef __attribute__((address_space(3))) unsigned int lds_uint;
__device__ __forceinline__ void gload_lds16(const ushort* g, ushort* l) {
  __builtin_amdgcn_global_load_lds((ga_uint*)g, (lds_uint*)l, 16, 0, 0);
}

// ---------------- K0: weight transpose + bf16 convert ----------------
// in: [512 k][512 n] fp32  ->  out: [512 n][512 k] bf16
__global__ void transpose_convert(const float* __restrict__ w1, const float* __restrict__ w2,
                                  ushort* __restrict__ o1, ushort* __restrict__ o2) {
  __shared__ float tile[64][65];
  const float* src = (blockIdx.z == 0) ? w1 : w2;
  ushort* dst = (blockIdx.z == 0) ? o1 : o2;
  const int n0 = blockIdx.x * 64, k0 = blockIdx.y * 64;
  const int tx = threadIdx.x, ty = threadIdx.y;  // 64 x 4
#pragma unroll
  for (int i = 0; i < 16; ++i) {
    int k = ty + i * 4;
    tile[k][tx] = src[(size_t)(k0 + k) * 512 + n0 + tx];
  }
  __syncthreads();
#pragma unroll
  for (int i = 0; i < 16; ++i) {
    int n = ty + i * 4;
    dst[(size_t)(n0 + n) * 512 + k0 + tx] = f2bf(tile[tx][n]);
  }
}

// ---------------- K0b: paths fp32 -> bf16, valid rows only ----------------
__global__ void convert_x(const float* __restrict__ X, const int* __restrict__ lengths,
                          ushort* __restrict__ Y) {
  const int stride = gridDim.x * blockDim.x;
  for (int i = blockIdx.x * blockDim.x + threadIdx.x; i < 16777216; i += stride) {
    const int row = i >> 6;                 // 0..262143
    const int l = row & 63, p = row >> 6;
    if (l < lengths[p]) {
      const float* s = X + (size_t)i * 8;
      float4 v0 = *(const float4*)s;
      float4 v1 = *(const float4*)(s + 4);
      u16x8 o = {f2bf(v0.x), f2bf(v0.y), f2bf(v0.z), f2bf(v0.w),
                 f2bf(v1.x), f2bf(v1.y), f2bf(v1.z), f2bf(v1.w)};
      *(u16x8*)(Y + (size_t)i * 8) = o;
    }
  }
}

// ---------------- K1: node-level 128x128x(K=512) bf16 GEMM + fused score ----------------
// m97 structure: global_load_lds_dwordx4 staging (no staging VALU), linear LDS,
// 2-barrier K-loop. Wave-uniform skip of (a) A-staging for fully-invalid 8-row
// groups, (b) MFMA 16-row sub-tiles with ms >= ceil(len/16). Invalid rows that
// do get staged read unwritten (garbage) bf16 — their scores are masked by
// node_softmax and weighted 0 in wsum, so the garbage never propagates.
// scores[m] += sum_n relu(A@B1 + b1)[m,n] * w2[n]   (atomic 4-way n-partial)
__launch_bounds__(256, 3)
__global__ void gemm_score_bf16(const ushort* __restrict__ A,     // [M][512] bf16 (valid rows only)
                                const ushort* __restrict__ Bt,    // [512 n][512 k] bf16
                                const float* __restrict__ bias,   // [512]
                                const float* __restrict__ wout,   // [512]
                                const int* __restrict__ lengths,  // [4096]
                                float* __restrict__ scores) {     // [M], pre-zeroed
  __shared__ ushort As[128 * 64] __attribute__((aligned(16)));
  __shared__ ushort Bs[128 * 64] __attribute__((aligned(16)));
  __shared__ float sred[2][128];
  const int tid = threadIdx.x;
  const int wv = tid >> 6, lane = tid & 63;
  const int ln = lane & 15, quad = lane >> 4;
  const int wm = wv & 1, wn = wv >> 1;   // wave quadrant in the 128x128 tile
  const int m0 = blockIdx.y * 128;
  const int nb = blockIdx.x * 128;
  const int p0 = m0 >> 6;                // 2 paths per m-tile

  const int len0 = lengths[p0], len1 = lengths[p0 + 1];
  const int mylen = wm ? len1 : len0;
  const int nms = (mylen + 15) >> 4;     // valid 16-row sub-tiles for this wave (1..4)

  float bv[4], w2v[4];
#pragma unroll
  for (int ns = 0; ns < 4; ++ns) {
    int n = nb + wn * 64 + ns * 16 + ln;
    bv[ns] = bias[n];
    w2v[ns] = wout[n];
  }

  f32x4 acc[4][4];
  const f32x4 zero = {0.f, 0.f, 0.f, 0.f};
#pragma unroll
  for (int i = 0; i < 4; ++i)
#pragma unroll
    for (int j = 0; j < 4; ++j) acc[i][j] = zero;

  for (int kc = 0; kc < 8; ++kc) {
    const int kb = kc * 64;
    __syncthreads();
    // stage A and B 128x64 bf16 tiles via LDS-DMA; linear [row][64] layout.
    // Wave wv of staging iter i covers rows r0..r0+7 (aligned, never straddles
    // the two paths). Skip A-load only when the WHOLE group is invalid ->
    // exec mask stays full for every issued DMA.
#pragma unroll
    for (int i = 0; i < 4; ++i) {
      const int id = i * 256 + tid;
      const int row = id >> 3, c = id & 7;          // 16B chunk c of row
      const int base = (i * 256 + (tid & ~63)) * 8; // wave-uniform lane0 slot
      const int r0 = i * 32 + wv * 8;               // first row of this wave's group
      const int rlen = (r0 < 64) ? len0 : len1;
      if ((r0 & 63) < rlen)
        gload_lds16(A + (size_t)(m0 + row) * 512 + kb + c * 8, &As[base]);
      gload_lds16(Bt + (size_t)(nb + row) * 512 + kb + c * 8, &Bs[base]);
    }
    __syncthreads();
#pragma unroll
    for (int k0 = 0; k0 < 2; ++k0) {
      bf16x8 bfr[4];
#pragma unroll
      for (int ns = 0; ns < 4; ++ns)
        bfr[ns] = *(const bf16x8*)(&Bs[(wn * 64 + ns * 16 + ln) * 64 + (quad + k0 * 4) * 8]);
#pragma unroll
      for (int ms = 0; ms < 4; ++ms) {
        if (ms < nms) {  // wave-uniform; static index -> acc stays in registers
          bf16x8 af = *(const bf16x8*)(&As[(wm * 64 + ms * 16 + ln) * 64 + (quad + k0 * 4) * 8]);
#pragma unroll
          for (int ns = 0; ns < 4; ++ns)
            acc[ms][ns] = __builtin_amdgcn_mfma_f32_16x16x32_bf16(af, bfr[ns], acc[ms][ns], 0, 0, 0);
        }
      }
    }
  }

  // epilogue: partial score over this block's 128 n
  // C/D layout: n = ln, m = quad*4 + r (within 16x16 subtile)
#pragma unroll
  for (int ms = 0; ms < 4; ++ms) {
#pragma unroll
    for (int r = 0; r < 4; ++r) {
      float s = 0.f;
      if (ms < nms) {
#pragma unroll
        for (int ns = 0; ns < 4; ++ns)
          s += fmaxf(acc[ms][ns][r] + bv[ns], 0.f) * w2v[ns];
        s += __shfl_xor(s, 1);
        s += __shfl_xor(s, 2);
        s += __shfl_xor(s, 4);
        s += __shfl_xor(s, 8);
      }
      if (ln == 0) sred[wn][wm * 64 + ms * 16 + quad * 4 + r] = s;
    }
  }
  __syncthreads();
  if (tid < 128) atomicAdd(&scores[m0 + tid], sred[0][tid] + sred[1][tid]);
}

// ---------------- K1b: fp32-staged GEMM+score (path-level call + fallback) ----------------
__launch_bounds__(256, 3)
__global__ void gemm_score_f32(const float* __restrict__ A,      // [M][512] fp32
                               const ushort* __restrict__ Bt,    // [512 n][512 k] bf16
                               const float* __restrict__ bias,   // [512]
                               const float* __restrict__ wout,   // [512]
                               float* __restrict__ scores) {     // [M], pre-zeroed
  __shared__ ushort As[128 * 64];
  __shared__ ushort Bs[128 * 64];
  __shared__ float sred[2][128];
  const int tid = threadIdx.x;
  const int wv = tid >> 6, lane = tid & 63;
  const int ln = lane & 15, quad = lane >> 4;
  const int wm = wv & 1, wn = wv >> 1;
  const int m0 = blockIdx.y * 128;
  const int nb = blockIdx.x * 128;

  float bv[4], w2v[4];
#pragma unroll
  for (int ns = 0; ns < 4; ++ns) {
    int n = nb + wn * 64 + ns * 16 + ln;
    bv[ns] = bias[n];
    w2v[ns] = wout[n];
  }

  f32x4 acc[4][4];
  const f32x4 zero = {0.f, 0.f, 0.f, 0.f};
#pragma unroll
  for (int i = 0; i < 4; ++i)
#pragma unroll
    for (int j = 0; j < 4; ++j) acc[i][j] = zero;

  int arow[4], brow[4];
#pragma unroll
  for (int ms = 0; ms < 4; ++ms) arow[ms] = wm * 64 + ms * 16 + ln;
#pragma unroll
  for (int ns = 0; ns < 4; ++ns) brow[ns] = wn * 64 + ns * 16 + ln;

  for (int kc = 0; kc < 8; ++kc) {
    const int kb = kc * 64;
    __syncthreads();
#pragma unroll
    for (int j = 0; j < 4; ++j) {
      int id = j * 256 + tid;
      int row = id >> 3, c = id & 7;
      int cs = (c ^ (row & 7)) * 8;
      const float* srcA = A + (size_t)(m0 + row) * 512 + kb + c * 8;
      float4 v0 = *(const float4*)srcA;
      float4 v1 = *(const float4*)(srcA + 4);
      u16x8 ua = {f2bf(v0.x), f2bf(v0.y), f2bf(v0.z), f2bf(v0.w),
                  f2bf(v1.x), f2bf(v1.y), f2bf(v1.z), f2bf(v1.w)};
      *(u16x8*)(&As[row * 64 + cs]) = ua;
      u16x8 ub = *(const u16x8*)(Bt + (size_t)(nb + row) * 512 + kb + c * 8);
      *(u16x8*)(&Bs[row * 64 + cs]) = ub;
    }
    __syncthreads();
#pragma unroll
    for (int k0 = 0; k0 < 2; ++k0) {
      bf16x8 af[4], bfr[4];
#pragma unroll
      for (int ms = 0; ms < 4; ++ms) {
        int r = arow[ms];
        af[ms] = *(const bf16x8*)(&As[r * 64 + (((quad + k0 * 4) ^ (r & 7)) * 8)]);
      }
#pragma unroll
      for (int ns = 0; ns < 4; ++ns) {
        int r = brow[ns];
        bfr[ns] = *(const bf16x8*)(&Bs[r * 64 + (((quad + k0 * 4) ^ (r & 7)) * 8)]);
      }
#pragma unroll
      for (int ms = 0; ms < 4; ++ms)
#pragma unroll
        for (int ns = 0; ns < 4; ++ns)
          acc[ms][ns] = __builtin_amdgcn_mfma_f32_16x16x32_bf16(af[ms], bfr[ns], acc[ms][ns], 0, 0, 0);
    }
  }

#pragma unroll
  for (int ms = 0; ms < 4; ++ms) {
#pragma unroll
    for (int r = 0; r < 4; ++r) {
      float s = 0.f;
#pragma unroll
      for (int ns = 0; ns < 4; ++ns)
        s += fmaxf(acc[ms][ns][r] + bv[ns], 0.f) * w2v[ns];
      s += __shfl_xor(s, 1);
      s += __shfl_xor(s, 2);
      s += __shfl_xor(s, 4);
      s += __shfl_xor(s, 8);
      if (ln == 0) sred[wn][wm * 64 + ms * 16 + quad * 4 + r] = s;
    }
  }
  __syncthreads();
  if (tid < 128) atomicAdd(&scores[m0 + tid], sred[0][tid] + sred[1][tid]);
}

// ---------------- K2: masked softmax over 64 nodes per path (in-place) ----------------
__global__ void node_softmax(float* __restrict__ s_wl, const int* __restrict__ lengths) {
  const int p = blockIdx.x * 4 + (threadIdx.x >> 6);
  const int l = threadIdx.x & 63;
  float s = s_wl[(size_t)p * 64 + l];
  const int len = lengths[p];
  const bool valid = l < len;
  float sv = valid ? s : -1e30f;
  float mx = sv;
  mx = fmaxf(mx, __shfl_xor(mx, 1));
  mx = fmaxf(mx, __shfl_xor(mx, 2));
  mx = fmaxf(mx, __shfl_xor(mx, 4));
  mx = fmaxf(mx, __shfl_xor(mx, 8));
  mx = fmaxf(mx, __shfl_xor(mx, 16));
  mx = fmaxf(mx, __shfl_xor(mx, 32));
  float e = valid ? __expf(sv - mx) : 0.f;
  float tot = e;
  tot += __shfl_xor(tot, 1);
  tot += __shfl_xor(tot, 2);
  tot += __shfl_xor(tot, 4);
  tot += __shfl_xor(tot, 8);
  tot += __shfl_xor(tot, 16);
  tot += __shfl_xor(tot, 32);
  s_wl[(size_t)p * 64 + l] = e / tot;
}

// ---------------- K3: paths_fea[p][d] = sum_{l<len} w[l] * X[p][l][d] ----------------
__global__ void wsum(const float* __restrict__ X, const float* __restrict__ wl,
                     const int* __restrict__ lengths, float* __restrict__ fea) {
  __shared__ float w[64];
  const int p = blockIdx.x, tid = threadIdx.x;  // 128 threads
  if (tid < 64) w[tid] = wl[(size_t)p * 64 + tid];
  __syncthreads();
  const int len = lengths[p];  // w[l] == 0 for l >= len
  const float* Xp = X + (size_t)p * 32768;
  const int d0 = tid * 4;
  float4 a = {0.f, 0.f, 0.f, 0.f};
  for (int l = 0; l < len; ++l) {
    float4 x = *(const float4*)(Xp + l * 512 + d0);
    a.x = fmaf(w[l], x.x, a.x);
    a.y = fmaf(w[l], x.y, a.y);
    a.z = fmaf(w[l], x.z, a.z);
    a.w = fmaf(w[l], x.w, a.w);
  }
  *(float4*)(fea + (size_t)p * 512 + d0) = a;
}

// ---------------- K4: softmax over 4096 path scores ----------------
__global__ void softmax_p(const float* __restrict__ a, float* __restrict__ aw) {
  const int tid = threadIdx.x;  // 256
  const int wv = tid >> 6;
  __shared__ float redm[4];
  __shared__ float reds[4];
  float v[16];
#pragma unroll
  for (int i = 0; i < 16; ++i) v[i] = a[i * 256 + tid];
  float mx = v[0];
#pragma unroll
  for (int i = 1; i < 16; ++i) mx = fmaxf(mx, v[i]);
  mx = fmaxf(mx, __shfl_xor(mx, 1));
  mx = fmaxf(mx, __shfl_xor(mx, 2));
  mx = fmaxf(mx, __shfl_xor(mx, 4));
  mx = fmaxf(mx, __shfl_xor(mx, 8));
  mx = fmaxf(mx, __shfl_xor(mx, 16));
  mx = fmaxf(mx, __shfl_xor(mx, 32));
  if ((tid & 63) == 0) redm[wv] = mx;
  __syncthreads();
  mx = fmaxf(fmaxf(redm[0], redm[1]), fmaxf(redm[2], redm[3]));
  float s = 0.f;
#pragma unroll
  for (int i = 0; i < 16; ++i) {
    v[i] = __expf(v[i] - mx);
    s += v[i];
  }
  s += __shfl_xor(s, 1);
  s += __shfl_xor(s, 2);
  s += __shfl_xor(s, 4);
  s += __shfl_xor(s, 8);
  s += __shfl_xor(s, 16);
  s += __shfl_xor(s, 32);
  if ((tid & 63) == 0) reds[wv] = s;
  __syncthreads();
  s = reds[0] + reds[1] + reds[2] + reds[3];
  const float inv = 1.f / s;
#pragma unroll
  for (int i = 0; i < 16; ++i) aw[i * 256 + tid] = v[i] * inv;
}

// ---------------- K5: user_fea[d] += sum_p aw[p] * fea[p][d] ----------------
__global__ void user_accum(const float* __restrict__ fea, const float* __restrict__ aw,
                           float* __restrict__ out) {
  const int g = blockIdx.x, tid = threadIdx.x;
  const int d0 = tid * 2;
  float ax = 0.f, ay = 0.f;
  for (int p = g * 64; p < g * 64 + 64; ++p) {
    float w = aw[p];
    float2 x = *(const float2*)(fea + (size_t)p * 512 + d0);
    ax = fmaf(w, x.x, ax);
    ay = fmaf(w, x.y, ay);
  }
  atomicAdd(out + d0, ax);
  atomicAdd(out + d0 + 1, ay);
}

extern "C" void kernel_launch(void* const* d_in, const int* in_sizes, int n_in,
                              void* d_out, int out_size, void* d_ws, size_t ws_size,
                              hipStream_t stream) {
  const float* paths   = (const float*)d_in[0];
  const int*   lengths = (const int*)d_in[1];
  const float* pW1     = (const float*)d_in[2];
  const float* pb1     = (const float*)d_in[3];
  const float* pw2     = (const float*)d_in[4];
  // d_in[5] = pb2: constant shift inside softmax -> cancels, unused
  const float* aW1     = (const float*)d_in[6];
  const float* ab1     = (const float*)d_in[7];
  const float* aw2     = (const float*)d_in[8];
  // d_in[9] = ab2: cancels, unused
  float* out = (float*)d_out;

  char* ws = (char*)d_ws;
  ushort* W1T  = (ushort*)ws;                   // 512 KB
  ushort* aW1T = (ushort*)(ws + 524288);        // 512 KB
  float* nsc   = (float*)(ws + 1048576);        // 1 MB [262144] node scores -> softmax in place -> wl
  float* fea   = (float*)(ws + 2097152);        // 8 MB [4096][512]
  float* psc   = (float*)(ws + 10485760);       // 16 KB [4096] path scores
  float* awp   = (float*)(ws + 10502144);       // 16 KB [4096]
  ushort* Xbf  = (ushort*)(ws + 16777216);      // 256 MB [262144][512] bf16 (valid rows only)
  const bool bf16_path = ws_size >= (16777216ull + 268435456ull);

  hipMemsetAsync(nsc, 0, 262144 * sizeof(float), stream);
  hipMemsetAsync(psc, 0, 4096 * sizeof(float), stream);
  hipMemsetAsync(d_out, 0, 512 * sizeof(float), stream);

  transpose_convert<<<dim3(8, 8, 2), dim3(64, 4), 0, stream>>>(pW1, aW1, W1T, aW1T);
  if (bf16_path) {
    convert_x<<<2048, 256, 0, stream>>>(paths, lengths, Xbf);
    // node-level: M = 262144 rows of X (bf16, LDS-DMA staging, length-pruned)
    gemm_score_bf16<<<dim3(4, 2048), 256, 0, stream>>>(Xbf, W1T, pb1, pw2, lengths, nsc);
  } else {
    // fallback: harness-verified fp32-staged path (no extra workspace)
    gemm_score_f32<<<dim3(4, 2048), 256, 0, stream>>>(paths, W1T, pb1, pw2, nsc);
  }
  node_softmax<<<1024, 256, 0, stream>>>(nsc, lengths);
  wsum<<<4096, 128, 0, stream>>>(paths, nsc, lengths, fea);
  // path-level: M = 4096 rows of fea
  gemm_score_f32<<<dim3(4, 32), 256, 0, stream>>>(fea, aW1T, ab1, aw2, psc);
  softmax_p<<<1, 256, 0, stream>>>(psc, awp);
  user_accum<<<64, 256, 0, stream>>>(fea, awp, out);
}

// Round 3
// 870.756 us; speedup vs baseline: 1.1322x; 1.0885x over previous
//
#include <hip/hip_runtime.h>

// P=4096, LMAX=64, D=512, H=512
typedef __attribute__((ext_vector_type(8))) short bf16x8;
typedef __attribute__((ext_vector_type(8))) unsigned short u16x8;
typedef __attribute__((ext_vector_type(4))) float f32x4;

__device__ __forceinline__ ushort f2bf(float x) {
  unsigned u = __float_as_uint(x);
  unsigned r = (u + 0x7fffu + ((u >> 16) & 1u)) >> 16;
  return (ushort)r;
}

// async global->LDS, 16B per lane. LDS base must be wave-uniform (lane0 slot);
// HW writes lane l at base + l*16. Only issued with a FULL exec mask.
typedef const __attribute__((address_space(1))) unsigned int ga_uint;
typedef __attribute__((address_space(3))) unsigned int lds_uint;
__device__ __forceinline__ void gload_lds16(const ushort* g, ushort* l) {
  __builtin_amdgcn_global_load_lds((ga_uint*)g, (lds_uint*)l, 16, 0, 0);
}

// ---------------- K0: weight transpose + bf16 convert ----------------
// in: [512 k][512 n] fp32  ->  out: [512 n][512 k] bf16
__global__ void transpose_convert(const float* __restrict__ w1, const float* __restrict__ w2,
                                  ushort* __restrict__ o1, ushort* __restrict__ o2) {
  __shared__ float tile[64][65];
  const float* src = (blockIdx.z == 0) ? w1 : w2;
  ushort* dst = (blockIdx.z == 0) ? o1 : o2;
  const int n0 = blockIdx.x * 64, k0 = blockIdx.y * 64;
  const int tx = threadIdx.x, ty = threadIdx.y;  // 64 x 4
#pragma unroll
  for (int i = 0; i < 16; ++i) {
    int k = ty + i * 4;
    tile[k][tx] = src[(size_t)(k0 + k) * 512 + n0 + tx];
  }
  __syncthreads();
#pragma unroll
  for (int i = 0; i < 16; ++i) {
    int n = ty + i * 4;
    dst[(size_t)(n0 + n) * 512 + k0 + tx] = f2bf(tile[tx][n]);
  }
}

// ---------------- K1: fully-fused node level — one block per path ----------------
// Per block p: scores = relu(X_p @ W1 + b1) @ w2 (64x512x512 bf16 MFMA GEMM,
// rows pruned to ceil(len/16) subtiles), masked softmax over len, then
// fea[p] = w . X_p (fp32 re-read, L2-warm). No atomics, no intermediate HBM.
// B (all 512 n) staged per 64-k chunk via global_load_lds with source-side XOR
// swizzle (linear LDS dest + inverse-swizzled source + swizzled read = rule 21);
// A reg-staged (fp32->bf16) with the same (row&7) XOR swizzle.
// Waves split n: wave wv owns n in [wv*128, wv*128+128).
// LDS: 8 KB A + 64 KB B + sred/wsm ~1.3 KB -> 2 blocks/CU.
__launch_bounds__(256, 2)
__global__ void node_fused(const float* __restrict__ X,        // [4096][64][512] fp32
                           const int* __restrict__ lengths,    // [4096]
                           const ushort* __restrict__ Bt,      // [512 n][512 k] bf16
                           const float* __restrict__ bias,     // [512]
                           const float* __restrict__ wout,     // [512]
                           float* __restrict__ fea) {          // [4096][512]
  __shared__ ushort As[64 * 64] __attribute__((aligned(16)));   // 8 KB
  __shared__ ushort Bs[512 * 64] __attribute__((aligned(16)));  // 64 KB
  __shared__ float sred[4][64];
  __shared__ float wsm[64];
  const int tid = threadIdx.x;
  const int wv = tid >> 6, lane = tid & 63;
  const int ln = lane & 15, quad = lane >> 4;
  const int p = blockIdx.x;
  const int len = lengths[p];
  const int nms = (len + 15) >> 4;  // valid 16-row m-subtiles (1..4), block-uniform
  const float* Xp = X + (size_t)p * 32768;

  float bv[8], w2v[8];
#pragma unroll
  for (int ns = 0; ns < 8; ++ns) {
    int n = wv * 128 + ns * 16 + ln;
    bv[ns] = bias[n];
    w2v[ns] = wout[n];
  }

  f32x4 acc[4][8];
  const f32x4 zero = {0.f, 0.f, 0.f, 0.f};
#pragma unroll
  for (int i = 0; i < 4; ++i)
#pragma unroll
    for (int j = 0; j < 8; ++j) acc[i][j] = zero;

  for (int kc = 0; kc < 8; ++kc) {
    const int kb = kc * 64;
    __syncthreads();
    // B: 512x64 bf16 via LDS-DMA; source chunk pre-swizzled so that the linear
    // DMA write leaves chunk j of row n at slot j^(n&7).
#pragma unroll
    for (int i = 0; i < 16; ++i) {
      const int id = i * 256 + tid;
      const int n = id >> 3, c = id & 7;
      const int base = (i * 256 + (tid & ~63)) * 8;  // wave-uniform lane0 slot
      gload_lds16(Bt + (size_t)n * 512 + kb + ((c ^ (n & 7)) * 8), &Bs[base]);
    }
    // A: up-to-64 x 64 reg-staged fp32->bf16, valid rows only, swizzled write.
    // Unwritten (invalid) rows hold garbage; their scores are masked below.
#pragma unroll
    for (int i = 0; i < 2; ++i) {
      const int id = i * 256 + tid;
      const int row = id >> 3, c = id & 7;
      if (row < len) {
        const float* s = Xp + row * 512 + kb + c * 8;
        float4 v0 = *(const float4*)s;
        float4 v1 = *(const float4*)(s + 4);
        u16x8 ua = {f2bf(v0.x), f2bf(v0.y), f2bf(v0.z), f2bf(v0.w),
                    f2bf(v1.x), f2bf(v1.y), f2bf(v1.z), f2bf(v1.w)};
        *(u16x8*)(&As[row * 64 + ((c ^ (row & 7)) * 8)]) = ua;
      }
    }
    __syncthreads();
#pragma unroll
    for (int k0 = 0; k0 < 2; ++k0) {
      bf16x8 af[4];
#pragma unroll
      for (int ms = 0; ms < 4; ++ms) {
        if (ms < nms) {
          int r = ms * 16 + ln;
          af[ms] = *(const bf16x8*)(&As[r * 64 + (((quad + k0 * 4) ^ (r & 7)) * 8)]);
        }
      }
#pragma unroll
      for (int ns = 0; ns < 8; ++ns) {
        int br = wv * 128 + ns * 16 + ln;
        bf16x8 bfr = *(const bf16x8*)(&Bs[br * 64 + (((quad + k0 * 4) ^ (br & 7)) * 8)]);
#pragma unroll
        for (int ms = 0; ms < 4; ++ms) {
          if (ms < nms)
            acc[ms][ns] = __builtin_amdgcn_mfma_f32_16x16x32_bf16(af[ms], bfr, acc[ms][ns], 0, 0, 0);
        }
      }
    }
  }

  // per-wave partial scores over its 128 n. C/D layout: n = ln, m = quad*4 + r.
#pragma unroll
  for (int ms = 0; ms < 4; ++ms) {
#pragma unroll
    for (int r = 0; r < 4; ++r) {
      float s = 0.f;
      if (ms < nms) {
#pragma unroll
        for (int ns = 0; ns < 8; ++ns)
          s += fmaxf(acc[ms][ns][r] + bv[ns], 0.f) * w2v[ns];
        s += __shfl_xor(s, 1);
        s += __shfl_xor(s, 2);
        s += __shfl_xor(s, 4);
        s += __shfl_xor(s, 8);
      }
      if (ln == 0) sred[wv][ms * 16 + quad * 4 + r] = s;
    }
  }
  __syncthreads();

  // masked softmax over the 64 node scores — wave 0 only
  if (wv == 0) {
    const int l = lane;
    float s = sred[0][l] + sred[1][l] + sred[2][l] + sred[3][l];
    const bool valid = l < len;
    float sv = valid ? s : -1e30f;  // garbage/NaN rows >= len never enter
    float mx = sv;
    mx = fmaxf(mx, __shfl_xor(mx, 1));
    mx = fmaxf(mx, __shfl_xor(mx, 2));
    mx = fmaxf(mx, __shfl_xor(mx, 4));
    mx = fmaxf(mx, __shfl_xor(mx, 8));
    mx = fmaxf(mx, __shfl_xor(mx, 16));
    mx = fmaxf(mx, __shfl_xor(mx, 32));
    float e = valid ? __expf(sv - mx) : 0.f;
    float tot = e;
    tot += __shfl_xor(tot, 1);
    tot += __shfl_xor(tot, 2);
    tot += __shfl_xor(tot, 4);
    tot += __shfl_xor(tot, 8);
    tot += __shfl_xor(tot, 16);
    tot += __shfl_xor(tot, 32);
    wsm[l] = e / tot;
  }
  __syncthreads();

  // fea[p][d] = sum_{l<len} wsm[l] * X_p[l][d]  (fp32, L2-warm re-read)
  const int d0 = tid * 2;
  float ax = 0.f, ay = 0.f;
#pragma unroll 4
  for (int l = 0; l < len; ++l) {
    float w = wsm[l];
    float2 x = *(const float2*)(Xp + l * 512 + d0);
    ax = fmaf(w, x.x, ax);
    ay = fmaf(w, x.y, ay);
  }
  float2 o = {ax, ay};
  *(float2*)(fea + (size_t)p * 512 + d0) = o;
}

// ---------------- K1b: fp32-staged GEMM+score (path-level, M=4096) ----------------
__launch_bounds__(256, 3)
__global__ void gemm_score_f32(const float* __restrict__ A,      // [M][512] fp32
                               const ushort* __restrict__ Bt,    // [512 n][512 k] bf16
                               const float* __restrict__ bias,   // [512]
                               const float* __restrict__ wout,   // [512]
                               float* __restrict__ scores) {     // [M], pre-zeroed
  __shared__ ushort As[128 * 64];
  __shared__ ushort Bs[128 * 64];
  __shared__ float sred[2][128];
  const int tid = threadIdx.x;
  const int wv = tid >> 6, lane = tid & 63;
  const int ln = lane & 15, quad = lane >> 4;
  const int wm = wv & 1, wn = wv >> 1;
  const int m0 = blockIdx.y * 128;
  const int nb = blockIdx.x * 128;

  float bv[4], w2v[4];
#pragma unroll
  for (int ns = 0; ns < 4; ++ns) {
    int n = nb + wn * 64 + ns * 16 + ln;
    bv[ns] = bias[n];
    w2v[ns] = wout[n];
  }

  f32x4 acc[4][4];
  const f32x4 zero = {0.f, 0.f, 0.f, 0.f};
#pragma unroll
  for (int i = 0; i < 4; ++i)
#pragma unroll
    for (int j = 0; j < 4; ++j) acc[i][j] = zero;

  int arow[4], brow[4];
#pragma unroll
  for (int ms = 0; ms < 4; ++ms) arow[ms] = wm * 64 + ms * 16 + ln;
#pragma unroll
  for (int ns = 0; ns < 4; ++ns) brow[ns] = wn * 64 + ns * 16 + ln;

  for (int kc = 0; kc < 8; ++kc) {
    const int kb = kc * 64;
    __syncthreads();
#pragma unroll
    for (int j = 0; j < 4; ++j) {
      int id = j * 256 + tid;
      int row = id >> 3, c = id & 7;
      int cs = (c ^ (row & 7)) * 8;
      const float* srcA = A + (size_t)(m0 + row) * 512 + kb + c * 8;
      float4 v0 = *(const float4*)srcA;
      float4 v1 = *(const float4*)(srcA + 4);
      u16x8 ua = {f2bf(v0.x), f2bf(v0.y), f2bf(v0.z), f2bf(v0.w),
                  f2bf(v1.x), f2bf(v1.y), f2bf(v1.z), f2bf(v1.w)};
      *(u16x8*)(&As[row * 64 + cs]) = ua;
      u16x8 ub = *(const u16x8*)(Bt + (size_t)(nb + row) * 512 + kb + c * 8);
      *(u16x8*)(&Bs[row * 64 + cs]) = ub;
    }
    __syncthreads();
#pragma unroll
    for (int k0 = 0; k0 < 2; ++k0) {
      bf16x8 af[4], bfr[4];
#pragma unroll
      for (int ms = 0; ms < 4; ++ms) {
        int r = arow[ms];
        af[ms] = *(const bf16x8*)(&As[r * 64 + (((quad + k0 * 4) ^ (r & 7)) * 8)]);
      }
#pragma unroll
      for (int ns = 0; ns < 4; ++ns) {
        int r = brow[ns];
        bfr[ns] = *(const bf16x8*)(&Bs[r * 64 + (((quad + k0 * 4) ^ (r & 7)) * 8)]);
      }
#pragma unroll
      for (int ms = 0; ms < 4; ++ms)
#pragma unroll
        for (int ns = 0; ns < 4; ++ns)
          acc[ms][ns] = __builtin_amdgcn_mfma_f32_16x16x32_bf16(af[ms], bfr[ns], acc[ms][ns], 0, 0, 0);
    }
  }

#pragma unroll
  for (int ms = 0; ms < 4; ++ms) {
#pragma unroll
    for (int r = 0; r < 4; ++r) {
      float s = 0.f;
#pragma unroll
      for (int ns = 0; ns < 4; ++ns)
        s += fmaxf(acc[ms][ns][r] + bv[ns], 0.f) * w2v[ns];
      s += __shfl_xor(s, 1);
      s += __shfl_xor(s, 2);
      s += __shfl_xor(s, 4);
      s += __shfl_xor(s, 8);
      if (ln == 0) sred[wn][wm * 64 + ms * 16 + quad * 4 + r] = s;
    }
  }
  __syncthreads();
  if (tid < 128) atomicAdd(&scores[m0 + tid], sred[0][tid] + sred[1][tid]);
}

// ---------------- K4: softmax over 4096 path scores ----------------
__global__ void softmax_p(const float* __restrict__ a, float* __restrict__ aw) {
  const int tid = threadIdx.x;  // 256
  const int wv = tid >> 6;
  __shared__ float redm[4];
  __shared__ float reds[4];
  float v[16];
#pragma unroll
  for (int i = 0; i < 16; ++i) v[i] = a[i * 256 + tid];
  float mx = v[0];
#pragma unroll
  for (int i = 1; i < 16; ++i) mx = fmaxf(mx, v[i]);
  mx = fmaxf(mx, __shfl_xor(mx, 1));
  mx = fmaxf(mx, __shfl_xor(mx, 2));
  mx = fmaxf(mx, __shfl_xor(mx, 4));
  mx = fmaxf(mx, __shfl_xor(mx, 8));
  mx = fmaxf(mx, __shfl_xor(mx, 16));
  mx = fmaxf(mx, __shfl_xor(mx, 32));
  if ((tid & 63) == 0) redm[wv] = mx;
  __syncthreads();
  mx = fmaxf(fmaxf(redm[0], redm[1]), fmaxf(redm[2], redm[3]));
  float s = 0.f;
#pragma unroll
  for (int i = 0; i < 16; ++i) {
    v[i] = __expf(v[i] - mx);
    s += v[i];
  }
  s += __shfl_xor(s, 1);
  s += __shfl_xor(s, 2);
  s += __shfl_xor(s, 4);
  s += __shfl_xor(s, 8);
  s += __shfl_xor(s, 16);
  s += __shfl_xor(s, 32);
  if ((tid & 63) == 0) reds[wv] = s;
  __syncthreads();
  s = reds[0] + reds[1] + reds[2] + reds[3];
  const float inv = 1.f / s;
#pragma unroll
  for (int i = 0; i < 16; ++i) aw[i * 256 + tid] = v[i] * inv;
}

// ---------------- K5: user_fea[d] += sum_p aw[p] * fea[p][d] ----------------
__global__ void user_accum(const float* __restrict__ fea, const float* __restrict__ aw,
                           float* __restrict__ out) {
  const int g = blockIdx.x, tid = threadIdx.x;
  const int d0 = tid * 2;
  float ax = 0.f, ay = 0.f;
  for (int p = g * 64; p < g * 64 + 64; ++p) {
    float w = aw[p];
    float2 x = *(const float2*)(fea + (size_t)p * 512 + d0);
    ax = fmaf(w, x.x, ax);
    ay = fmaf(w, x.y, ay);
  }
  atomicAdd(out + d0, ax);
  atomicAdd(out + d0 + 1, ay);
}

extern "C" void kernel_launch(void* const* d_in, const int* in_sizes, int n_in,
                              void* d_out, int out_size, void* d_ws, size_t ws_size,
                              hipStream_t stream) {
  const float* paths   = (const float*)d_in[0];
  const int*   lengths = (const int*)d_in[1];
  const float* pW1     = (const float*)d_in[2];
  const float* pb1     = (const float*)d_in[3];
  const float* pw2     = (const float*)d_in[4];
  // d_in[5] = pb2: constant shift inside softmax -> cancels, unused
  const float* aW1     = (const float*)d_in[6];
  const float* ab1     = (const float*)d_in[7];
  const float* aw2     = (const float*)d_in[8];
  // d_in[9] = ab2: cancels, unused
  float* out = (float*)d_out;

  char* ws = (char*)d_ws;
  ushort* W1T  = (ushort*)ws;                   // 512 KB
  ushort* aW1T = (ushort*)(ws + 524288);        // 512 KB
  float* fea   = (float*)(ws + 2097152);        // 8 MB [4096][512]
  float* psc   = (float*)(ws + 10485760);       // 16 KB [4096] path scores
  float* awp   = (float*)(ws + 10502144);       // 16 KB [4096]

  hipMemsetAsync(psc, 0, 4096 * sizeof(float), stream);
  hipMemsetAsync(d_out, 0, 512 * sizeof(float), stream);

  transpose_convert<<<dim3(8, 8, 2), dim3(64, 4), 0, stream>>>(pW1, aW1, W1T, aW1T);
  // node level fully fused: GEMM+score -> masked softmax -> weighted sum
  node_fused<<<4096, 256, 0, stream>>>(paths, lengths, W1T, pb1, pw2, fea);
  // path-level: M = 4096 rows of fea
  gemm_score_f32<<<dim3(4, 32), 256, 0, stream>>>(fea, aW1T, ab1, aw2, psc);
  softmax_p<<<1, 256, 0, stream>>>(psc, awp);
  user_accum<<<64, 256, 0, stream>>>(fea, awp, out);
}